// Round 3
// baseline (474.743 us; speedup 1.0000x reference)
//
#include <hip/hip_runtime.h>
#include <hip/hip_bf16.h>

#define NN 8192
#define FIN 512
#define FOUT 256

typedef __attribute__((ext_vector_type(8))) short short8;
typedef __attribute__((ext_vector_type(4))) float float4v;
typedef __attribute__((ext_vector_type(16))) float float16v;

__device__ __forceinline__ short f2bf(float f) {
    union { float f; unsigned u; } v; v.f = f;
    unsigned r = (v.u + 0x7FFFu + ((v.u >> 16) & 1u)) >> 16;
    return (short)r;
}

// ---------------- Kernel 0: Wt[n][k] = bf16(W[k][n]), tiled transpose ----------------
__global__ __launch_bounds__(256) void wt_kernel(const float* __restrict__ W,
                                                 short* __restrict__ Wt) {
    __shared__ short tile[32][33];
    int tx = threadIdx.x & 31, ty = threadIdx.x >> 5;   // 32 x 8
    int k0 = blockIdx.x * 32, n0 = blockIdx.y * 32;
#pragma unroll
    for (int r = 0; r < 32; r += 8)
        tile[ty + r][tx] = f2bf(W[(size_t)(k0 + ty + r) * FOUT + n0 + tx]);
    __syncthreads();
#pragma unroll
    for (int r = 0; r < 32; r += 8)
        Wt[(size_t)(n0 + ty + r) * FIN + k0 + tx] = tile[tx][ty + r];
}

// ---------------- Kernel 1: h_t[n][m] = bf16((x@W)[m][n]); fused f_src/f_dst ----------------
__global__ __launch_bounds__(256) void h_kernel(const float* __restrict__ x,
                                                const short* __restrict__ Wt,
                                                const float* __restrict__ a,
                                                short* __restrict__ h_t,
                                                float* __restrict__ f_src,
                                                float* __restrict__ f_dst) {
    int wave = (blockIdx.x << 2) + (threadIdx.x >> 6);
    int lane = threadIdx.x & 63;
    int m0 = (wave & 511) << 4;
    int n0 = (wave >> 9) << 6;
    int lr = lane & 15, lq = lane >> 4;

    const float* xrow = x + (size_t)(m0 + lr) * FIN + lq * 8;
    const short* wbase = Wt + (size_t)(n0 + lr) * FIN + lq * 8;

    float4v acc[4] = {};
    for (int k0 = 0; k0 < FIN; k0 += 32) {
        float4v xa = *(const float4v*)(xrow + k0);
        float4v xb = *(const float4v*)(xrow + k0 + 4);
        short8 av;
        av[0] = f2bf(xa[0]); av[1] = f2bf(xa[1]); av[2] = f2bf(xa[2]); av[3] = f2bf(xa[3]);
        av[4] = f2bf(xb[0]); av[5] = f2bf(xb[1]); av[6] = f2bf(xb[2]); av[7] = f2bf(xb[3]);
#pragma unroll
        for (int ct = 0; ct < 4; ct++) {
            short8 bv = *(const short8*)(wbase + (size_t)ct * 16 * FIN + k0);
            acc[ct] = __builtin_amdgcn_mfma_f32_16x16x32_bf16(av, bv, acc[ct], 0, 0, 0);
        }
    }
    float s_part[4] = {0.f, 0.f, 0.f, 0.f};
    float d_part[4] = {0.f, 0.f, 0.f, 0.f};
#pragma unroll
    for (int ct = 0; ct < 4; ct++) {
        int n = n0 + ct * 16 + lr;
        float al = a[n], ar = a[FOUT + n];
#pragma unroll
        for (int reg = 0; reg < 4; reg++) {
            float hv = acc[ct][reg];
            s_part[reg] = fmaf(hv, al, s_part[reg]);
            d_part[reg] = fmaf(hv, ar, d_part[reg]);
            h_t[(size_t)n * NN + (m0 + lq * 4 + reg)] = f2bf(hv);
        }
    }
#pragma unroll
    for (int off = 1; off < 16; off <<= 1) {
#pragma unroll
        for (int reg = 0; reg < 4; reg++) {
            s_part[reg] += __shfl_xor(s_part[reg], off);
            d_part[reg] += __shfl_xor(d_part[reg], off);
        }
    }
    const float LOG2E = 1.4426950408889634f;
    if (lr == 0) {
#pragma unroll
        for (int reg = 0; reg < 4; reg++) {
            atomicAdd(&f_src[m0 + lq * 4 + reg], s_part[reg] * LOG2E);
            atomicAdd(&f_dst[m0 + lq * 4 + reg], d_part[reg] * LOG2E);
        }
    }
}

// ---------------- Kernel 2: fused masked-softmax-numerator @ h, pipelined ----------------
// Block: 256 thr = 4 waves, tile 128 rows x 256 feats, j-slice jlen.
// Wave = 32 rows x 256 feats as 1x8 row of 32x32x16 MFMA tiles (acc 8x16 = 128 VGPR).
// P (A-operand) computed IN REGISTERS from adj/f_src/f_dst (lane l: m=l&31, k=(l>>5)*8+i).
// B (h_t rows) double-buffered in LDS, XOR-swizzled, staged a full 64-j chunk ahead.
// Raw s_barrier + lgkmcnt(0) only -> global loads stay in flight across barriers.
__global__ __launch_bounds__(256, 2) void gat_kernel(const int* __restrict__ adj,
                                                     const short* __restrict__ h_t,
                                                     const float* __restrict__ f_src,
                                                     const float* __restrict__ f_dst,
                                                     float* __restrict__ Opart,
                                                     float* __restrict__ lpart,
                                                     int jlen) {
    __shared__ short Bb[2][256 * 64];    // [buf][feat*64 + swizzled j] , 64 KB total

    const int t = threadIdx.x;
    const int lane = t & 63;
    const int w = t >> 6;
    const int l31 = lane & 31, lq = lane >> 5;
    const int i0 = blockIdx.x * 128;
    const int slice = blockIdx.y;
    const int jbase = slice * jlen;
    const int myrow = i0 + w * 32 + l31;
    const int rsw = l31 & 7;             // read-side swizzle key
    const int swz = t & 7;               // stage-side swizzle key
    const int nchunk = jlen >> 6;

    const float fs = f_src[myrow];
    const int* adjL = adj + (size_t)myrow * NN + jbase + lq * 8;
    const float* fdL = f_dst + jbase + lq * 8;
    const short* hrow = h_t + (size_t)t * NN + jbase;   // thread t stages feature row t

    float16v acc[8] = {};
    float lp = 0.f;

    // rolling 2-kstep-ahead register prefetch of adj + f_dst
    int4 aj[2][2];
    float4 fd[2][2];
    aj[0][0] = *(const int4*)(adjL);       aj[0][1] = *(const int4*)(adjL + 4);
    fd[0][0] = *(const float4*)(fdL);      fd[0][1] = *(const float4*)(fdL + 4);
    aj[1][0] = *(const int4*)(adjL + 16);  aj[1][1] = *(const int4*)(adjL + 20);
    fd[1][0] = *(const float4*)(fdL + 16); fd[1][1] = *(const float4*)(fdL + 20);

    // prologue: stage chunk 0 into buffer 0 (swizzled: chunk c8 -> slot c8^swz)
    {
#pragma unroll
        for (int q = 0; q < 8; q++) {
            short8 b = *(const short8*)(hrow + q * 8);
            *(short8*)(&Bb[0][0] + t * 64 + ((q ^ swz) << 3)) = b;
        }
    }
    __syncthreads();

    for (int c = 0; c < nchunk; ++c) {
        short* curb = &Bb[c & 1][0];
        short* nxtb = &Bb[(c & 1) ^ 1][0];
        const int jn = (c + 1 < nchunk) ? (c + 1) * 64 : 0;   // next chunk (wraps, harmless)

        auto kstep = [&](int kk) {
            const int s = kk & 1;
            const int4 A0 = aj[s][0], A1 = aj[s][1];
            const float4 F0 = fd[s][0], F1 = fd[s][1];
            // prefetch kstep+2 into this slot (stays in flight across the barrier)
            int off = (c * 4 + kk + 2) * 16;
            if (off >= jlen) off -= jlen;
            aj[s][0] = *(const int4*)(adjL + off);
            aj[s][1] = *(const int4*)(adjL + off + 4);
            fd[s][0] = *(const float4*)(fdL + off);
            fd[s][1] = *(const float4*)(fdL + off + 4);

            const int* ai0 = (const int*)&A0;
            const int* ai1 = (const int*)&A1;
            const float* ff0 = (const float*)&F0;
            const float* ff1 = (const float*)&F1;
            short8 af;
#pragma unroll
            for (int q = 0; q < 4; q++) {
                float y = fs + ff0[q];
                y = fmaxf(y, 0.2f * y);          // leaky_relu (log2-scaled domain)
                float e = exp2f(y);
                float p = ai0[q] ? e : 0.f;
                lp += p;
                af[q] = f2bf(p);
            }
#pragma unroll
            for (int q = 0; q < 4; q++) {
                float y = fs + ff1[q];
                y = fmaxf(y, 0.2f * y);
                float e = exp2f(y);
                float p = ai1[q] ? e : 0.f;
                lp += p;
                af[4 + q] = f2bf(p);
            }
            const int cb = ((kk * 2 + lq) ^ rsw) << 3;
#pragma unroll
            for (int nt = 0; nt < 8; nt++) {
                short8 b = *(const short8*)(curb + (nt * 32 + l31) * 64 + cb);
                acc[nt] = __builtin_amdgcn_mfma_f32_32x32x16_bf16(af, b, acc[nt], 0, 0, 0);
            }
        };

        // stage first half of next chunk, compute kk=0,1
        short8 s0 = *(const short8*)(hrow + jn + 0);
        short8 s1 = *(const short8*)(hrow + jn + 8);
        short8 s2 = *(const short8*)(hrow + jn + 16);
        short8 s3 = *(const short8*)(hrow + jn + 24);
        kstep(0);
        kstep(1);
        *(short8*)(nxtb + t * 64 + ((0 ^ swz) << 3)) = s0;
        *(short8*)(nxtb + t * 64 + ((1 ^ swz) << 3)) = s1;
        *(short8*)(nxtb + t * 64 + ((2 ^ swz) << 3)) = s2;
        *(short8*)(nxtb + t * 64 + ((3 ^ swz) << 3)) = s3;
        // second half, compute kk=2,3
        short8 s4 = *(const short8*)(hrow + jn + 32);
        short8 s5 = *(const short8*)(hrow + jn + 40);
        short8 s6 = *(const short8*)(hrow + jn + 48);
        short8 s7 = *(const short8*)(hrow + jn + 56);
        kstep(2);
        kstep(3);
        *(short8*)(nxtb + t * 64 + ((4 ^ swz) << 3)) = s4;
        *(short8*)(nxtb + t * 64 + ((5 ^ swz) << 3)) = s5;
        *(short8*)(nxtb + t * 64 + ((6 ^ swz) << 3)) = s6;
        *(short8*)(nxtb + t * 64 + ((7 ^ swz) << 3)) = s7;

        // raw barrier: only LDS drain; global prefetches stay in flight
        asm volatile("s_waitcnt lgkmcnt(0)" ::: "memory");
        asm volatile("s_barrier" ::: "memory");
    }

    // ---- epilogue ----
    lp += __shfl_xor(lp, 32);
    if (lq == 0) lpart[(size_t)slice * NN + myrow] = lp;

    float* ob = Opart + ((size_t)slice * NN + i0 + w * 32) * FOUT;
#pragma unroll
    for (int nt = 0; nt < 8; nt++) {
        int n = nt * 32 + l31;
#pragma unroll
        for (int reg = 0; reg < 16; reg++) {
            int row = (reg & 3) + 8 * (reg >> 2) + 4 * lq;   // verified 32x32 C/D mapping
            ob[(size_t)row * FOUT + n] = acc[nt][reg];
        }
    }
}

// ---------------- Kernel 3: combine partials: out = sum_s O_s / sum_s l_s ----------------
__global__ __launch_bounds__(256) void combine_kernel(const float* __restrict__ Opart,
                                                      const float* __restrict__ lpart,
                                                      float* __restrict__ out, int slices) {
    int i = blockIdx.x, n = threadIdx.x;
    float o = 0.f, l = 0.f;
    for (int s = 0; s < slices; s++) {
        o += Opart[((size_t)s * NN + i) * FOUT + n];
        l += lpart[(size_t)s * NN + i];
    }
    out[(size_t)i * FOUT + n] = o / l;
}

extern "C" void kernel_launch(void* const* d_in, const int* in_sizes, int n_in,
                              void* d_out, int out_size, void* d_ws, size_t ws_size,
                              hipStream_t stream) {
    const float* x   = (const float*)d_in[0];
    const int*   adj = (const int*)d_in[1];
    const float* W   = (const float*)d_in[2];
    const float* a   = (const float*)d_in[3];
    float* out = (float*)d_out;

    char* ws = (char*)d_ws;
    short* h_t   = (short*)ws;                                   // 4 MB
    short* Wt    = (short*)(ws + (4u << 20));                    // 256 KB
    float* f_src = (float*)(ws + (4u << 20) + (256u << 10));     // 32 KB
    float* f_dst = (float*)(ws + (4u << 20) + (288u << 10));     // 32 KB
    float* lpart = (float*)(ws + (4u << 20) + (320u << 10));     // <=256 KB
    float* Opart = (float*)(ws + (8u << 20));                    // slices * 8 MB

    const size_t OSLICE = (size_t)NN * FOUT * 4;                 // 8 MB per slice
    int slices = 2;
    if (ws_size >= (8u << 20) + 8 * OSLICE) slices = 8;
    else if (ws_size >= (8u << 20) + 4 * OSLICE) slices = 4;
    int jlen = NN / slices;

    hipMemsetAsync(f_src, 0, 2 * NN * sizeof(float), stream);
    wt_kernel<<<dim3(FIN / 32, FOUT / 32), 256, 0, stream>>>(W, Wt);
    h_kernel<<<512, 256, 0, stream>>>(x, Wt, a, h_t, f_src, f_dst);
    gat_kernel<<<dim3(NN / 128, slices), 256, 0, stream>>>(adj, h_t, f_src, f_dst,
                                                           Opart, lpart, jlen);
    combine_kernel<<<NN, 256, 0, stream>>>(Opart, lpart, out, slices);
}